// Round 6
// baseline (424.774 us; speedup 1.0000x reference)
//
#include <hip/hip_runtime.h>
#include <hip/hip_bf16.h>

#define S_ 128
#define N_ 384
#define CM 256
#define CH 32
#define CZ 128

typedef __attribute__((ext_vector_type(8))) __bf16 bf16x8;
typedef __attribute__((ext_vector_type(4))) float f32x4;

union pack4 { __hip_bfloat16 h[4]; uint2 u; };

// ---- Kernel P: fused weight prep -----------------------------------------
__global__ __launch_bounds__(256) void k_prep(const float* __restrict__ w1,
                                              const float* __restrict__ w2,
                                              const float* __restrict__ wout,
                                              __hip_bfloat16* __restrict__ wt12,
                                              __hip_bfloat16* __restrict__ woutT)
{
    const int b = blockIdx.x, t = threadIdx.x;
    if (b < 64) {
        const float* w = (b < CH) ? w1 : w2;
        wt12[b * CM + t] = __float2bfloat16(w[(size_t)t * CH + (b & 31)]);
    } else {
        const int z = b - 64;
        for (int cd = t; cd < CH*CH; cd += 256)
            woutT[(size_t)z * (CH*CH) + cd] = __float2bfloat16(wout[(size_t)cd * CZ + z]);
    }
}

// ---- Kernel R: reciprocal norm -------------------------------------------
__global__ __launch_bounds__(N_) void k_rnorm(const float* __restrict__ mask,
                                              float* __restrict__ RN)
{
    const int i = blockIdx.x, j = threadIdx.x;
    float acc = 0.f;
    #pragma unroll 8
    for (int s = 0; s < S_; ++s)
        acc += mask[s*N_ + i] * mask[s*N_ + j];
    RN[i*N_ + j] = 1.0f / (acc + 1e-3f);
}

// ---- Kernel 1: LayerNorm + dual projection via MFMA (unchanged) ----------
#define LNR 264
__global__ __launch_bounds__(256) void k_lnp(
    const float* __restrict__ m, const float* __restrict__ mask,
    const float* __restrict__ gamma, const float* __restrict__ beta,
    const float* __restrict__ b1, const float* __restrict__ b2,
    const __hip_bfloat16* __restrict__ wt12,
    __hip_bfloat16* __restrict__ At, __hip_bfloat16* __restrict__ Bt)
{
    __shared__ __hip_bfloat16 lnS[128 * LNR];
    __shared__ float msk[128];
    const int n0 = blockIdx.x * 16, s0 = blockIdx.y * 8;
    const int t = threadIdx.x, wave = t >> 6, lane = t & 63;
    const int l15 = lane & 15, quad = lane >> 4;

    if (t < 128) msk[t] = mask[(s0 + (t & 7))*N_ + n0 + (t >> 3)];

    float4 g  = ((const float4*)gamma)[lane];
    float4 be = ((const float4*)beta)[lane];
    for (int i = 0; i < 32; ++i) {
        const int row = wave*32 + i;
        const int n = row >> 3, s = row & 7;
        float4 x = ((const float4*)(m + ((size_t)((s0+s)*N_ + n0 + n)) * CM))[lane];
        float sum = x.x + x.y + x.z + x.w;
        float ssq = x.x*x.x + x.y*x.y + x.z*x.z + x.w*x.w;
        #pragma unroll
        for (int off = 32; off >= 1; off >>= 1) {
            sum += __shfl_xor(sum, off, 64);
            ssq += __shfl_xor(ssq, off, 64);
        }
        const float mean = sum * (1.0f/CM);
        const float var  = ssq * (1.0f/CM) - mean*mean;
        const float rstd = rsqrtf(var + 1e-5f);
        pack4 pk;
        pk.h[0] = __float2bfloat16((x.x - mean)*rstd*g.x + be.x);
        pk.h[1] = __float2bfloat16((x.y - mean)*rstd*g.y + be.y);
        pk.h[2] = __float2bfloat16((x.z - mean)*rstd*g.z + be.z);
        pk.h[3] = __float2bfloat16((x.w - mean)*rstd*g.w + be.w);
        *(uint2*)&lnS[row*LNR + lane*4] = pk.u;
    }
    __syncthreads();

    f32x4 acc[2][4];
    const f32x4 z4 = {0.f,0.f,0.f,0.f};
    #pragma unroll
    for (int mt = 0; mt < 2; ++mt)
        #pragma unroll
        for (int nt = 0; nt < 4; ++nt) acc[mt][nt] = z4;

    #pragma unroll
    for (int kk = 0; kk < 8; ++kk) {
        bf16x8 a0 = *(const bf16x8*)&lnS[(wave*32      + l15)*LNR + kk*32 + quad*8];
        bf16x8 a1 = *(const bf16x8*)&lnS[(wave*32 + 16 + l15)*LNR + kk*32 + quad*8];
        #pragma unroll
        for (int nt = 0; nt < 4; ++nt) {
            bf16x8 wv = *(const bf16x8*)&wt12[(size_t)(nt*16 + l15)*CM + kk*32 + quad*8];
            acc[0][nt] = __builtin_amdgcn_mfma_f32_16x16x32_bf16(a0, wv, acc[0][nt], 0,0,0);
            acc[1][nt] = __builtin_amdgcn_mfma_f32_16x16x32_bf16(a1, wv, acc[1][nt], 0,0,0);
        }
    }

    #pragma unroll
    for (int nt = 0; nt < 4; ++nt) {
        const int ncol = nt*16 + l15;
        const int sel = ncol >> 5, c = ncol & 31;
        const float bias = sel ? b2[c] : b1[c];
        __hip_bfloat16* dst = sel ? Bt : At;
        #pragma unroll
        for (int mt = 0; mt < 2; ++mt) {
            const int rowb = wave*32 + mt*16 + quad*4;
            const int n_loc = rowb >> 3, s_loc = rowb & 7;
            pack4 pk;
            #pragma unroll
            for (int r = 0; r < 4; ++r)
                pk.h[r] = __float2bfloat16((acc[mt][nt][r] + bias) * msk[rowb + r]);
            *(uint2*)&dst[((size_t)(n0 + n_loc)*CH + c)*S_ + s0 + s_loc] = pk.u;
        }
    }
}

// ---- Kernel 2: persistent pipelined outer-product + w_out GEMM -----------
// R4 skeleton (XCD-banded walk, FETCH-clean; 2x74.2KB double-buffered O;
// ONE barrier/tile) with R4's two measured bugs fixed:
//  BUG-A (was: wf[32] persistent pinned 128 regs -> load pipeline starved,
//         spill): wf now loaded per-tile inside stage-3, two 16-frag chunks;
//         liveness disjoint from acc.
//  BUG-B (was: stage-3 placed before stage-2 loads even issued -> barrier
//         stalled on full load latency): ALL 32 stage-2 b128 loads for tile
//         t are ISSUED FIRST, then stage-3 of tile t-1 (several us of
//         LDS+MFMA) covers their L2 latency, then stage-2 MFMA consumes.
// launch_bounds(512,1): occupancy is LDS-bound at 1 block/CU regardless;
// give the allocator the full register budget (peak live ~230 regs:
// 128 pending loads + 64 wf + oacc + addr). 8 waves resident guaranteed.
#define OR 1160
#define OSZ (32*OR)
#define NT 18

#define ISSUE_K(AF, BF, KK)                                                 \
    _Pragma("unroll") for (int mt = 0; mt < 4; ++mt)                        \
        AF[mt] = *(const bf16x8*)&At[dA + aBase[mt] + (KK)*32];             \
    _Pragma("unroll") for (int nt = 0; nt < 4; ++nt)                        \
        BF[nt] = *(const bf16x8*)&Bt[dB + bBase[nt] + (KK)*32];

#define S2MFMA(AF, BF)                                                      \
    _Pragma("unroll") for (int nt = 0; nt < 4; ++nt)                        \
        _Pragma("unroll") for (int mt = 0; mt < 4; ++mt)                    \
            acc[nt][mt] = __builtin_amdgcn_mfma_f32_16x16x32_bf16(          \
                BF[nt], AF[mt], acc[nt][mt], 0, 0, 0);

#define OWRITE(BUF)                                                         \
  {                                                                         \
    __hip_bfloat16* Ob = &O[(BUF)*OSZ];                                     \
    _Pragma("unroll") for (int mt = 0; mt < 4; ++mt) {                      \
      const int Mcol = mq*64 + mt*16 + l15;                                 \
      const int i_l = Mcol >> 5, c = Mcol & 31;                             \
      _Pragma("unroll") for (int nt = 0; nt < 4; ++nt) {                    \
        const int Nrow = nh*64 + nt*16 + quad*4;                            \
        const int j_l = Nrow >> 5, d0 = Nrow & 31;                          \
        const int p = i_l*4 + j_l;                                          \
        pack4 pk;                                                           \
        _Pragma("unroll") for (int r = 0; r < 4; ++r)                       \
          pk.h[r] = __float2bfloat16(acc[nt][mt][r]);                       \
        *(uint2*)&Ob[p*OR + c*36 + d0] = pk.u;                              \
      }                                                                     \
    }                                                                       \
  }

#define STAGE3(PI0, PJ0, BUF)                                               \
  {                                                                         \
    const __hip_bfloat16* Op = &O[(BUF)*OSZ];                               \
    f32x4 oacc[2]; oacc[0] = z4; oacc[1] = z4;                              \
    _Pragma("unroll") for (int h = 0; h < 2; ++h) {                         \
      bf16x8 wf[16];                                                        \
      _Pragma("unroll") for (int k2 = 0; k2 < 16; ++k2)                     \
        wf[k2] = *(const bf16x8*)&woutT[(size_t)(zb + l15)*(CH*CH)          \
                                        + (h*16 + k2)*32 + quad*8];         \
      _Pragma("unroll") for (int k2 = 0; k2 < 16; ++k2) {                   \
        const int kk = h*16 + k2;                                           \
        _Pragma("unroll") for (int mt2 = 0; mt2 < 2; ++mt2) {               \
          bf16x8 a = *(const bf16x8*)&Op[(mt2*16 + l15)*OR + kk*36 + quad*8];\
          oacc[mt2] = __builtin_amdgcn_mfma_f32_16x16x32_bf16(              \
              a, wf[k2], oacc[mt2], 0, 0, 0);                               \
        }                                                                   \
      }                                                                     \
    }                                                                       \
    _Pragma("unroll") for (int mt2 = 0; mt2 < 2; ++mt2)                     \
      _Pragma("unroll") for (int r = 0; r < 4; ++r) {                       \
        const int p = mt2*16 + quad*4 + r;                                  \
        const int i = (PI0) + (p >> 2), j = (PJ0) + (p & 3);                \
        out[((size_t)(i*N_ + j))*CZ + zb + l15] = (oacc[mt2][r] + bz)       \
                                                  * RN[i*N_ + j];           \
      }                                                                     \
  }

__global__ __launch_bounds__(512, 1) void k_opm(
    const __hip_bfloat16* __restrict__ At, const __hip_bfloat16* __restrict__ Bt,
    const float* __restrict__ RN, const __hip_bfloat16* __restrict__ woutT,
    const float* __restrict__ bout, float* __restrict__ out)
{
    __shared__ __hip_bfloat16 O[2*OSZ];   // 148.5 KB, double-buffered
    const int t = threadIdx.x;
    const int wave = t >> 6, lane = t & 63;
    const int l15 = lane & 15, quad = lane >> 4;
    const int mq = wave & 3, nh = wave >> 2;
    const int zb = wave * 16;
    const f32x4 z4 = {0.f,0.f,0.f,0.f};
    const float bz = bout[zb + l15];

    // tile-invariant per-lane offsets
    int aBase[4], bBase[4];
    #pragma unroll
    for (int mt = 0; mt < 4; ++mt) {
        const int Mrow = mq*64 + mt*16 + l15;           // = i_l*32 + c
        aBase[mt] = ((Mrow >> 5)*CH + (Mrow & 31))*S_ + quad*8;
    }
    #pragma unroll
    for (int nt = 0; nt < 4; ++nt) {
        const int Ncol = nh*64 + nt*16 + l15;           // = j_l*32 + d
        bBase[nt] = ((Ncol >> 5)*CH + (Ncol & 31))*S_ + quad*8;
    }

    // XCD-banded walk (R4-proven FETCH-clean): xcd owns a 12-j-blk band,
    // i sweeps fastest within the band.
    const int slot = blockIdx.x >> 3, xcd = blockIdx.x & 7;

    // ---- prologue: tile 0 -> buf 0 (no stage-3 yet) ----
    int q  = slot * NT;
    int i0 = (q % 48) * 8;
    int j0 = (xcd*12 + q/48) * 4;
    {
        const int dA = i0*CH*S_, dB = j0*CH*S_;
        bf16x8 aF0[4], bF0[4], aF1[4], bF1[4], aF2[4], bF2[4], aF3[4], bF3[4];
        ISSUE_K(aF0, bF0, 0)
        ISSUE_K(aF1, bF1, 1)
        ISSUE_K(aF2, bF2, 2)
        ISSUE_K(aF3, bF3, 3)
        f32x4 acc[4][4];
        #pragma unroll
        for (int nt = 0; nt < 4; ++nt)
            #pragma unroll
            for (int mt = 0; mt < 4; ++mt) acc[nt][mt] = z4;
        S2MFMA(aF0, bF0)
        S2MFMA(aF1, bF1)
        S2MFMA(aF2, bF2)
        S2MFMA(aF3, bF3)
        OWRITE(0)
    }
    __syncthreads();
    int pi0 = i0, pj0 = j0;

    #pragma unroll 1
    for (int tl = 1; tl < NT; ++tl) {
        q  = slot * NT + tl;
        i0 = (q % 48) * 8;
        j0 = (xcd*12 + q/48) * 4;
        const int dA = i0*CH*S_, dB = j0*CH*S_;

        // A: ISSUE all stage-2 loads for tile tl (latency hides under B)
        bf16x8 aF0[4], bF0[4], aF1[4], bF1[4], aF2[4], bF2[4], aF3[4], bF3[4];
        ISSUE_K(aF0, bF0, 0)
        ISSUE_K(aF1, bF1, 1)
        ISSUE_K(aF2, bF2, 2)
        ISSUE_K(aF3, bF3, 3)

        // B: stage-3 of tile tl-1 from buf (tl-1)&1 (LDS+MFMA, several us)
        STAGE3(pi0, pj0, (tl-1)&1)

        // C: stage-2 MFMA on landed operands -> buf tl&1
        f32x4 acc[4][4];
        #pragma unroll
        for (int nt = 0; nt < 4; ++nt)
            #pragma unroll
            for (int mt = 0; mt < 4; ++mt) acc[nt][mt] = z4;
        S2MFMA(aF0, bF0)
        S2MFMA(aF1, bF1)
        S2MFMA(aF2, bF2)
        S2MFMA(aF3, bF3)
        OWRITE(tl&1)

        __syncthreads();        // orders buf reuse; one barrier per tile
        pi0 = i0; pj0 = j0;
    }
    // epilogue: finish last tile
    STAGE3(pi0, pj0, (NT-1)&1)
}

extern "C" void kernel_launch(void* const* d_in, const int* in_sizes, int n_in,
                              void* d_out, int out_size, void* d_ws, size_t ws_size,
                              hipStream_t stream)
{
    const float* m    = (const float*)d_in[0];
    const float* mask = (const float*)d_in[1];
    const float* gam  = (const float*)d_in[2];
    const float* bet  = (const float*)d_in[3];
    const float* w1   = (const float*)d_in[4];
    const float* b1   = (const float*)d_in[5];
    const float* w2   = (const float*)d_in[6];
    const float* b2   = (const float*)d_in[7];
    const float* wout = (const float*)d_in[8];
    const float* bout = (const float*)d_in[9];
    float* out = (float*)d_out;

    __hip_bfloat16* At    = (__hip_bfloat16*)d_ws;                 // [N][CH][S]
    __hip_bfloat16* Bt    = At + (size_t)N_ * CH * S_;             // [N][CH][S]
    __hip_bfloat16* woutT = Bt + (size_t)N_ * CH * S_;             // [CZ][1024]
    __hip_bfloat16* wt12  = woutT + (size_t)CZ * CH * CH;          // [64][256]
    float*          RN    = (float*)(wt12 + (size_t)64 * CM);      // [N][N]

    k_prep<<<192, 256, 0, stream>>>(w1, w2, wout, wt12, woutT);
    k_rnorm<<<N_, N_, 0, stream>>>(mask, RN);
    dim3 gl(24, 16);
    k_lnp<<<gl, 256, 0, stream>>>(m, mask, gam, bet, b1, b2, wt12, At, Bt);
    k_opm<<<256, 512, 0, stream>>>(At, Bt, RN, woutT, bout, out);
}

// Round 7
// 323.576 us; speedup vs baseline: 1.3127x; 1.3127x over previous
//
#include <hip/hip_runtime.h>
#include <hip/hip_bf16.h>

#define S_ 128
#define N_ 384
#define CM 256
#define CH 32
#define CZ 128

typedef __attribute__((ext_vector_type(8))) __bf16 bf16x8;
typedef __attribute__((ext_vector_type(4))) float f32x4;

union pack4 { __hip_bfloat16 h[4]; uint2 u; };

// ---- Kernel P: fused prep (wt12 + woutT + RN) — one launch ---------------
// blocks 0..63    : wt12[64][256] bf16 = [w1|w2]^T     (t < 256 active)
// blocks 64..191  : woutT[z][cd] bf16
// blocks 192..575 : RN[i][j] = 1/(mask^T mask + eps)   (384 thr = j)
__global__ __launch_bounds__(384) void k_prep(const float* __restrict__ w1,
                                              const float* __restrict__ w2,
                                              const float* __restrict__ wout,
                                              const float* __restrict__ mask,
                                              __hip_bfloat16* __restrict__ wt12,
                                              __hip_bfloat16* __restrict__ woutT,
                                              float* __restrict__ RN)
{
    const int b = blockIdx.x, t = threadIdx.x;
    if (b < 64) {
        if (t < 256) {
            const float* w = (b < CH) ? w1 : w2;
            wt12[b * CM + t] = __float2bfloat16(w[(size_t)t * CH + (b & 31)]);
        }
    } else if (b < 192) {
        const int z = b - 64;
        for (int cd = t; cd < CH*CH; cd += 384)
            woutT[(size_t)z * (CH*CH) + cd] = __float2bfloat16(wout[(size_t)cd * CZ + z]);
    } else {
        const int i = b - 192, j = t;
        float acc = 0.f;
        #pragma unroll 8
        for (int s = 0; s < S_; ++s)
            acc += mask[s*N_ + i] * mask[s*N_ + j];
        RN[i*N_ + j] = 1.0f / (acc + 1e-3f);
    }
}

// ---- Kernel 1: LayerNorm + dual projection via MFMA (R0, unchanged) ------
#define LNR 264
__global__ __launch_bounds__(256) void k_lnp(
    const float* __restrict__ m, const float* __restrict__ mask,
    const float* __restrict__ gamma, const float* __restrict__ beta,
    const float* __restrict__ b1, const float* __restrict__ b2,
    const __hip_bfloat16* __restrict__ wt12,
    __hip_bfloat16* __restrict__ At, __hip_bfloat16* __restrict__ Bt)
{
    __shared__ __hip_bfloat16 lnS[128 * LNR];
    __shared__ float msk[128];
    const int n0 = blockIdx.x * 16, s0 = blockIdx.y * 8;
    const int t = threadIdx.x, wave = t >> 6, lane = t & 63;
    const int l15 = lane & 15, quad = lane >> 4;

    if (t < 128) msk[t] = mask[(s0 + (t & 7))*N_ + n0 + (t >> 3)];

    float4 g  = ((const float4*)gamma)[lane];
    float4 be = ((const float4*)beta)[lane];
    for (int i = 0; i < 32; ++i) {
        const int row = wave*32 + i;
        const int n = row >> 3, s = row & 7;
        float4 x = ((const float4*)(m + ((size_t)((s0+s)*N_ + n0 + n)) * CM))[lane];
        float sum = x.x + x.y + x.z + x.w;
        float ssq = x.x*x.x + x.y*x.y + x.z*x.z + x.w*x.w;
        #pragma unroll
        for (int off = 32; off >= 1; off >>= 1) {
            sum += __shfl_xor(sum, off, 64);
            ssq += __shfl_xor(ssq, off, 64);
        }
        const float mean = sum * (1.0f/CM);
        const float var  = ssq * (1.0f/CM) - mean*mean;
        const float rstd = rsqrtf(var + 1e-5f);
        pack4 pk;
        pk.h[0] = __float2bfloat16((x.x - mean)*rstd*g.x + be.x);
        pk.h[1] = __float2bfloat16((x.y - mean)*rstd*g.y + be.y);
        pk.h[2] = __float2bfloat16((x.z - mean)*rstd*g.z + be.z);
        pk.h[3] = __float2bfloat16((x.w - mean)*rstd*g.w + be.w);
        *(uint2*)&lnS[row*LNR + lane*4] = pk.u;
    }
    __syncthreads();

    f32x4 acc[2][4];
    const f32x4 z4 = {0.f,0.f,0.f,0.f};
    #pragma unroll
    for (int mt = 0; mt < 2; ++mt)
        #pragma unroll
        for (int nt = 0; nt < 4; ++nt) acc[mt][nt] = z4;

    #pragma unroll
    for (int kk = 0; kk < 8; ++kk) {
        bf16x8 a0 = *(const bf16x8*)&lnS[(wave*32      + l15)*LNR + kk*32 + quad*8];
        bf16x8 a1 = *(const bf16x8*)&lnS[(wave*32 + 16 + l15)*LNR + kk*32 + quad*8];
        #pragma unroll
        for (int nt = 0; nt < 4; ++nt) {
            bf16x8 wv = *(const bf16x8*)&wt12[(size_t)(nt*16 + l15)*CM + kk*32 + quad*8];
            acc[0][nt] = __builtin_amdgcn_mfma_f32_16x16x32_bf16(a0, wv, acc[0][nt], 0,0,0);
            acc[1][nt] = __builtin_amdgcn_mfma_f32_16x16x32_bf16(a1, wv, acc[1][nt], 0,0,0);
        }
    }

    #pragma unroll
    for (int nt = 0; nt < 4; ++nt) {
        const int ncol = nt*16 + l15;
        const int sel = ncol >> 5, c = ncol & 31;
        const float bias = sel ? b2[c] : b1[c];
        __hip_bfloat16* dst = sel ? Bt : At;
        #pragma unroll
        for (int mt = 0; mt < 2; ++mt) {
            const int rowb = wave*32 + mt*16 + quad*4;
            const int n_loc = rowb >> 3, s_loc = rowb & 7;
            pack4 pk;
            #pragma unroll
            for (int r = 0; r < 4; ++r)
                pk.h[r] = __float2bfloat16((acc[mt][nt][r] + bias) * msk[rowb + r]);
            *(uint2*)&dst[((size_t)(n0 + n_loc)*CH + c)*S_ + s0 + s_loc] = pk.u;
        }
    }
}

// ---- Kernel 2: fused MFMA outer-product + w_out GEMM ---------------------
// EXACT R0 structure (the 200 us champion: 8x8 pairs, 512 thr, grid 48x48,
// 145 KB O, stage-2 wave = M-half x N-quarter acc[4][8], stage-3 exclusive
// 16-z slice per wave) with ONE surgical change:
//   R0 preloaded wf[32] (128 VGPR) BEFORE stage-2, which together with
//   acc[4][8] (128 acc-regs) filled the entire 252-reg budget -> zero
//   headroom for in-flight At/Bt loads -> stage-2 load serialization
//   (MfmaUtil 15.7%). wf is now loaded AFTER the barrier, in two 16-frag
//   chunks (R3-proven pattern) -> stage-2 gets ~120 free VGPRs for load
//   pipelining; stage-3 liveness is wf-chunk 64 + oacc 16.
#define OR 1160
__global__ __launch_bounds__(512) void k_opm(
    const __hip_bfloat16* __restrict__ At, const __hip_bfloat16* __restrict__ Bt,
    const float* __restrict__ RN, const __hip_bfloat16* __restrict__ woutT,
    const float* __restrict__ bout, float* __restrict__ out)
{
    __shared__ __hip_bfloat16 O[64 * OR];   // 145 KB
    const int t = threadIdx.x;
    const int wave = t >> 6, lane = t & 63;
    const int l15 = lane & 15, quad = lane >> 4;
    const int i0 = blockIdx.x * 8, j0 = blockIdx.y * 8;
    const int mhalf = wave & 1, nquad = wave >> 1;

    // ---- stage 2: acc[nt][mt] = D[(j,d)][(i,c)] ----
    f32x4 acc[4][8];
    const f32x4 z4 = {0.f,0.f,0.f,0.f};
    #pragma unroll
    for (int nt = 0; nt < 4; ++nt)
        #pragma unroll
        for (int mt = 0; mt < 8; ++mt) acc[nt][mt] = z4;

    const __hip_bfloat16* Ag[8];
    #pragma unroll
    for (int mt = 0; mt < 8; ++mt) {
        const int Mrow = mhalf*128 + mt*16 + l15;     // = i_l*32 + c
        Ag[mt] = At + ((size_t)(i0 + (Mrow >> 5)) * CH + (Mrow & 31)) * S_ + quad*8;
    }
    const __hip_bfloat16* Bg[4];
    #pragma unroll
    for (int nt = 0; nt < 4; ++nt) {
        const int Ncol = nquad*64 + nt*16 + l15;      // = j_l*32 + d
        Bg[nt] = Bt + ((size_t)(j0 + (Ncol >> 5)) * CH + (Ncol & 31)) * S_ + quad*8;
    }

    #pragma unroll
    for (int kk = 0; kk < 4; ++kk) {
        bf16x8 af[8], bfr[4];
        #pragma unroll
        for (int mt = 0; mt < 8; ++mt) af[mt] = *(const bf16x8*)(Ag[mt] + kk*32);
        #pragma unroll
        for (int nt = 0; nt < 4; ++nt) bfr[nt] = *(const bf16x8*)(Bg[nt] + kk*32);
        #pragma unroll
        for (int nt = 0; nt < 4; ++nt)
            #pragma unroll
            for (int mt = 0; mt < 8; ++mt)
                acc[nt][mt] = __builtin_amdgcn_mfma_f32_16x16x32_bf16(
                    bfr[nt], af[mt], acc[nt][mt], 0, 0, 0);
    }

    // ---- O writes: col(l15) -> (i,c); row(quad,r) -> (j,d), r = consec d ----
    #pragma unroll
    for (int mt = 0; mt < 8; ++mt) {
        const int Mcol = mhalf*128 + mt*16 + l15;
        const int i_l = Mcol >> 5, c = Mcol & 31;
        #pragma unroll
        for (int nt = 0; nt < 4; ++nt) {
            const int Nrow = nquad*64 + nt*16 + quad*4;
            const int j_l = Nrow >> 5, d0 = Nrow & 31;
            const int p = i_l*8 + j_l;
            pack4 pk;
            #pragma unroll
            for (int r = 0; r < 4; ++r) pk.h[r] = __float2bfloat16(acc[nt][mt][r]);
            *(uint2*)&O[p*OR + c*36 + d0] = pk.u;
        }
    }
    __syncthreads();

    // ---- stage 3: wave's exclusive 16-z slice; wf loaded HERE (post-acc
    //      death), two 16-frag chunks, oacc carried across chunks ----
    const int zb = wave * 16;
    f32x4 oacc[4];
    #pragma unroll
    for (int mt = 0; mt < 4; ++mt) oacc[mt] = z4;

    #pragma unroll
    for (int h = 0; h < 2; ++h) {
        bf16x8 wf[16];
        #pragma unroll
        for (int k2 = 0; k2 < 16; ++k2)
            wf[k2] = *(const bf16x8*)&woutT[(size_t)(zb + l15) * (CH*CH)
                                            + (h*16 + k2)*32 + quad*8];
        #pragma unroll
        for (int k2 = 0; k2 < 16; ++k2) {
            const int kk = h*16 + k2;
            #pragma unroll
            for (int mt = 0; mt < 4; ++mt) {
                bf16x8 a = *(const bf16x8*)&O[(mt*16 + l15)*OR + kk*36 + quad*8];
                oacc[mt] = __builtin_amdgcn_mfma_f32_16x16x32_bf16(
                    a, wf[k2], oacc[mt], 0, 0, 0);
            }
        }
    }

    // ---- epilogue: col(l15) -> z, row(quad,r) -> p ----
    const int zc = zb + l15;
    const float bz = bout[zc];
    #pragma unroll
    for (int mt = 0; mt < 4; ++mt) {
        #pragma unroll
        for (int r = 0; r < 4; ++r) {
            const int p = mt*16 + quad*4 + r;
            const int i = i0 + (p >> 3), j = j0 + (p & 7);
            const float rn = RN[i*N_ + j];
            out[((size_t)(i*N_ + j))*CZ + zc] = (oacc[mt][r] + bz) * rn;
        }
    }
}

extern "C" void kernel_launch(void* const* d_in, const int* in_sizes, int n_in,
                              void* d_out, int out_size, void* d_ws, size_t ws_size,
                              hipStream_t stream)
{
    const float* m    = (const float*)d_in[0];
    const float* mask = (const float*)d_in[1];
    const float* gam  = (const float*)d_in[2];
    const float* bet  = (const float*)d_in[3];
    const float* w1   = (const float*)d_in[4];
    const float* b1   = (const float*)d_in[5];
    const float* w2   = (const float*)d_in[6];
    const float* b2   = (const float*)d_in[7];
    const float* wout = (const float*)d_in[8];
    const float* bout = (const float*)d_in[9];
    float* out = (float*)d_out;

    __hip_bfloat16* At    = (__hip_bfloat16*)d_ws;                 // [N][CH][S]
    __hip_bfloat16* Bt    = At + (size_t)N_ * CH * S_;             // [N][CH][S]
    __hip_bfloat16* woutT = Bt + (size_t)N_ * CH * S_;             // [CZ][1024]
    __hip_bfloat16* wt12  = woutT + (size_t)CZ * CH * CH;          // [64][256]
    float*          RN    = (float*)(wt12 + (size_t)64 * CM);      // [N][N]

    k_prep<<<576, 384, 0, stream>>>(w1, w2, wout, mask, wt12, woutT, RN);
    dim3 gl(24, 16);
    k_lnp<<<gl, 256, 0, stream>>>(m, mask, gam, bet, b1, b2, wt12, At, Bt);
    dim3 grid(N_ / 8, N_ / 8);
    k_opm<<<grid, 512, 0, stream>>>(At, Bt, RN, woutT, bout, out);
}